// Round 1
// baseline (246.582 us; speedup 1.0000x reference)
//
#include <hip/hip_runtime.h>
#include <cstddef>
#include <math.h>

#define NN 50000
#define DEG 16
#define NEG_SLOPE 0.2f

// ---------------- GEMM [N,K] x [K,128] -> feat[N,128] + el/er (H heads) ----------
// block 256 threads; 64 rows/block; each thread: 4 rows x 8 cols register tile.
template<int K, int H>
__launch_bounds__(256)
__global__ void gemm128_k(const float* __restrict__ A, const float* __restrict__ W,
                          const float* __restrict__ al, const float* __restrict__ ar,
                          float* __restrict__ feat, float* __restrict__ el, float* __restrict__ er)
{
    __shared__ float As[64][36];      // 32-k chunk, pad to 36 (16B-aligned rows, bank spread)
    __shared__ float Bs[32 * 128];
    const int tid = threadIdx.x;
    const int tx = tid & 15;          // col group: cols 8*tx .. 8*tx+7
    const int ty = tid >> 4;          // rows ty*4 .. ty*4+3
    const int row0 = blockIdx.x * 64;

    float acc[4][8];
#pragma unroll
    for (int i = 0; i < 4; i++)
#pragma unroll
        for (int j = 0; j < 8; j++) acc[i][j] = 0.f;

    for (int kc = 0; kc < K; kc += 32) {
        __syncthreads();
        { // As: 64 rows x 32 floats; 4 threads/row, 2 float4 each
            int r = tid >> 2;
            int part = tid & 3;
            int gr = row0 + r; if (gr > NN - 1) gr = NN - 1;
            const float4* s4 = (const float4*)(A + (size_t)gr * K + kc);
            float4 v0 = s4[part * 2];
            float4 v1 = s4[part * 2 + 1];
            *(float4*)&As[r][part * 8] = v0;
            *(float4*)&As[r][part * 8 + 4] = v1;
        }
        { // Bs: rows kc..kc+31 of W, contiguous 4096 floats
            const float4* s4 = (const float4*)(W + (size_t)kc * 128);
            float4* d4 = (float4*)Bs;
#pragma unroll
            for (int q = 0; q < 4; q++) d4[tid + 256 * q] = s4[tid + 256 * q];
        }
        __syncthreads();
        const float4* Bs4 = (const float4*)Bs;
#pragma unroll
        for (int kk = 0; kk < 32; kk++) {
            float4 b0 = Bs4[kk * 32 + tx * 2];
            float4 b1 = Bs4[kk * 32 + tx * 2 + 1];
#pragma unroll
            for (int i = 0; i < 4; i++) {
                float a = As[ty * 4 + i][kk];
                acc[i][0] += a * b0.x; acc[i][1] += a * b0.y;
                acc[i][2] += a * b0.z; acc[i][3] += a * b0.w;
                acc[i][4] += a * b1.x; acc[i][5] += a * b1.y;
                acc[i][6] += a * b1.z; acc[i][7] += a * b1.w;
            }
        }
    }

    // el/er: head h covers cols [h*128/H, (h+1)*128/H); G = lanes per head group
    constexpr int G = 16 / H;
    const int h = tx / G;
    float pel[4] = {0, 0, 0, 0}, per[4] = {0, 0, 0, 0};
#pragma unroll
    for (int j = 0; j < 8; j++) {
        float va = al[h * (128 / H) + (tx % G) * 8 + j];
        float vr = ar[h * (128 / H) + (tx % G) * 8 + j];
#pragma unroll
        for (int i = 0; i < 4; i++) { pel[i] += acc[i][j] * va; per[i] += acc[i][j] * vr; }
    }
#pragma unroll
    for (int m = 1; m < G; m <<= 1) {
#pragma unroll
        for (int i = 0; i < 4; i++) {
            pel[i] += __shfl_xor(pel[i], m);
            per[i] += __shfl_xor(per[i], m);
        }
    }
#pragma unroll
    for (int i = 0; i < 4; i++) {
        int r = row0 + ty * 4 + i;
        if (r < NN) {
            float4 o0 = make_float4(acc[i][0], acc[i][1], acc[i][2], acc[i][3]);
            float4 o1 = make_float4(acc[i][4], acc[i][5], acc[i][6], acc[i][7]);
            *(float4*)&feat[(size_t)r * 128 + tx * 8] = o0;
            *(float4*)&feat[(size_t)r * 128 + tx * 8 + 4] = o1;
            if ((tx % G) == 0) { el[r * H + h] = pel[i]; er[r * H + h] = per[i]; }
        }
    }
}

// ---------------- edge softmax + aggregate, 128 output cols, H heads -------------
// one wave per dst node; lanes 0..15 hold the 16 in-edge logits per head group.
template<int H>
__launch_bounds__(256)
__global__ void agg128_k(const float* __restrict__ feat, const float* __restrict__ el,
                         const float* __restrict__ er, const int* __restrict__ src,
                         const float* __restrict__ bias, float* __restrict__ out, int do_relu)
{
    __shared__ float s_alpha[4][16 * H];
    __shared__ int s_src[4][DEG];
    const int tid = threadIdx.x;
    const int w = tid >> 6, lane = tid & 63;
    const int node = blockIdx.x * 4 + w;
    const int j = lane & 15;
    const int h = lane >> 4;     // 0..3 (H=1: groups compute identical values)

    int s = src[node * DEG + j];
    float e;
    if (H == 4) e = el[s * 4 + h] + er[node * 4 + h];
    else        e = el[s] + er[node];
    e = (e > 0.f) ? e : NEG_SLOPE * e;
    float mx = e;
#pragma unroll
    for (int d = 1; d < 16; d <<= 1) mx = fmaxf(mx, __shfl_xor(mx, d));
    float ex = expf(e - mx);
    float den = ex;
#pragma unroll
    for (int d = 1; d < 16; d <<= 1) den += __shfl_xor(den, d);
    float alpha = ex / den;
    if (H == 4) s_alpha[w][h * 16 + j] = alpha;
    else if (lane < 16) s_alpha[w][j] = alpha;
    if (lane < 16) s_src[w][j] = s;
    __syncthreads();

    const int c0 = lane, c1 = lane + 64;
    float acc0 = 0.f, acc1 = 0.f;
#pragma unroll
    for (int jj = 0; jj < DEG; jj++) {
        int sj = s_src[w][jj];
        const float* base = feat + (size_t)sj * 128;
        float a0, a1;
        if (H == 4) { a0 = s_alpha[w][(c0 >> 5) * 16 + jj]; a1 = s_alpha[w][(c1 >> 5) * 16 + jj]; }
        else        { a0 = s_alpha[w][jj]; a1 = a0; }
        acc0 += a0 * base[c0];
        acc1 += a1 * base[c1];
    }
    float v0 = acc0 + bias[c0];
    float v1 = acc1 + bias[c1];
    if (do_relu) { v0 = fmaxf(v0, 0.f); v1 = fmaxf(v1, 0.f); }
    out[(size_t)node * 128 + c0] = v0;
    out[(size_t)node * 128 + c1] = v1;
}

// ---------------- GEMM [N,128] x [128,40] -> feat2[N,40] + el2/er2 (1 head) ------
__launch_bounds__(256)
__global__ void gemm40_k(const float* __restrict__ A, const float* __restrict__ W,
                         const float* __restrict__ al, const float* __restrict__ ar,
                         float* __restrict__ feat, float* __restrict__ el, float* __restrict__ er)
{
    __shared__ float As[32][132];
    __shared__ float Ws[128 * 40];
    const int tid = threadIdx.x;
    const int tx = tid & 31;       // lanes tx<20 own cols {2tx, 2tx+1}
    const int ty = tid >> 5;       // rows ty*4 .. ty*4+3 (32 rows/block)
    const int row0 = blockIdx.x * 32;

    { // stage W2 (5120 floats) into LDS
        const float4* s4 = (const float4*)W;
        float4* d4 = (float4*)Ws;
#pragma unroll
        for (int q = 0; q < 5; q++) d4[tid + 256 * q] = s4[tid + 256 * q];
    }
    { // stage A rows: 32 x 128; 8 threads/row, 4 float4 each
        int r = tid >> 3;
        int gr = row0 + r; if (gr > NN - 1) gr = NN - 1;
        const float4* s4 = (const float4*)(A + (size_t)gr * 128);
#pragma unroll
        for (int q = 0; q < 4; q++) {
            float4 v = s4[(tid & 7) + 8 * q];
            *(float4*)&As[r][4 * ((tid & 7) + 8 * q)] = v;
        }
    }
    __syncthreads();

    const int ctx = (tx < 20) ? tx : 19;
    const float2* Wf2 = (const float2*)Ws;
    float acc[4][2] = {};
#pragma unroll 4
    for (int k = 0; k < 128; k++) {
        float2 wv = Wf2[k * 20 + ctx];
#pragma unroll
        for (int i = 0; i < 4; i++) {
            float a = As[ty * 4 + i][k];
            acc[i][0] += a * wv.x;
            acc[i][1] += a * wv.y;
        }
    }
    float pel[4], per[4];
#pragma unroll
    for (int i = 0; i < 4; i++) {
        float vl = 0.f, vr = 0.f;
        if (tx < 20) {
            vl = acc[i][0] * al[2 * ctx] + acc[i][1] * al[2 * ctx + 1];
            vr = acc[i][0] * ar[2 * ctx] + acc[i][1] * ar[2 * ctx + 1];
        }
        pel[i] = vl; per[i] = vr;
    }
#pragma unroll
    for (int m = 1; m < 32; m <<= 1) {   // reduce within 32-lane half-wave (= one ty)
#pragma unroll
        for (int i = 0; i < 4; i++) {
            pel[i] += __shfl_xor(pel[i], m);
            per[i] += __shfl_xor(per[i], m);
        }
    }
#pragma unroll
    for (int i = 0; i < 4; i++) {
        int r = row0 + ty * 4 + i;
        if (r < NN) {
            if (tx < 20) *(float2*)&feat[(size_t)r * 40 + 2 * tx] = make_float2(acc[i][0], acc[i][1]);
            if (tx == 0) { el[r] = pel[i]; er[r] = per[i]; }
        }
    }
}

// ---------------- edge softmax + aggregate 40 cols + log_softmax -----------------
__launch_bounds__(256)
__global__ void agg40_ls_k(const float* __restrict__ feat, const float* __restrict__ el,
                           const float* __restrict__ er, const int* __restrict__ src,
                           const float* __restrict__ bias, float* __restrict__ out)
{
    __shared__ float s_alpha[4][DEG];
    __shared__ int s_src[4][DEG];
    const int tid = threadIdx.x;
    const int w = tid >> 6, lane = tid & 63;
    const int node = blockIdx.x * 4 + w;
    const int j = lane & 15;

    int s = src[node * DEG + j];
    float e = el[s] + er[node];
    e = (e > 0.f) ? e : NEG_SLOPE * e;
    float mx = e;
#pragma unroll
    for (int d = 1; d < 16; d <<= 1) mx = fmaxf(mx, __shfl_xor(mx, d));
    float ex = expf(e - mx);
    float den = ex;
#pragma unroll
    for (int d = 1; d < 16; d <<= 1) den += __shfl_xor(den, d);
    if (lane < 16) { s_alpha[w][j] = ex / den; s_src[w][j] = s; }
    __syncthreads();

    float v;
    if (lane < 40) {
        float acc = 0.f;
#pragma unroll
        for (int jj = 0; jj < DEG; jj++)
            acc += s_alpha[w][jj] * feat[(size_t)s_src[w][jj] * 40 + lane];
        v = acc + bias[lane];
    } else v = -INFINITY;

    float m2 = v;
#pragma unroll
    for (int d = 1; d < 64; d <<= 1) m2 = fmaxf(m2, __shfl_xor(m2, d));
    float pe = (lane < 40) ? expf(v - m2) : 0.f;
    float se = pe;
#pragma unroll
    for (int d = 1; d < 64; d <<= 1) se += __shfl_xor(se, d);
    if (lane < 40) out[(size_t)node * 40 + lane] = v - m2 - logf(se);
}

extern "C" void kernel_launch(void* const* d_in, const int* in_sizes, int n_in,
                              void* d_out, int out_size, void* d_ws, size_t ws_size,
                              hipStream_t stream)
{
    const float* features = (const float*)d_in[0];
    const int*   src      = (const int*)d_in[1];
    // d_in[2] = dst: structurally repeat(arange(N),16) -> unused
    const float* W1  = (const float*)d_in[3];
    const float* al1 = (const float*)d_in[4];
    const float* ar1 = (const float*)d_in[5];
    const float* b1  = (const float*)d_in[6];
    const float* Wh  = (const float*)d_in[7];
    const float* alh = (const float*)d_in[8];
    const float* arh = (const float*)d_in[9];
    const float* bh  = (const float*)d_in[10];
    const float* W2  = (const float*)d_in[11];
    const float* al2 = (const float*)d_in[12];
    const float* ar2 = (const float*)d_in[13];
    const float* b2  = (const float*)d_in[14];
    float* out = (float*)d_out;

    float* ws    = (float*)d_ws;
    float* featb = ws;                           // N*128 (also reused as feat2 N*40)
    float* hb    = featb + (size_t)NN * 128;     // N*128
    float* el1   = hb    + (size_t)NN * 128;     // N*4
    float* er1   = el1   + (size_t)NN * 4;       // N*4
    float* elA   = er1   + (size_t)NN * 4;       // N
    float* erA   = elA   + NN;                   // N

    dim3 blk(256);
    // layer 1: GATConv(256 -> 32x4 heads)
    gemm128_k<256, 4><<<782, blk, 0, stream>>>(features, W1, al1, ar1, featb, el1, er1);
    agg128_k<4><<<12500, blk, 0, stream>>>(featb, el1, er1, src, b1, hb, 1);
    // hidden: GATConv(128 -> 128, 1 head)
    gemm128_k<128, 1><<<782, blk, 0, stream>>>(hb, Wh, alh, arh, featb, elA, erA);
    agg128_k<1><<<12500, blk, 0, stream>>>(featb, elA, erA, src, bh, hb, 1);
    // layer 2: GATConv(128 -> 40, 1 head) + log_softmax
    gemm40_k<<<1563, blk, 0, stream>>>(hb, W2, al2, ar2, featb, elA, erA);
    agg40_ls_k<<<12500, blk, 0, stream>>>(featb, elA, erA, src, b2, out);
}

// Round 2
// 204.474 us; speedup vs baseline: 1.2059x; 1.2059x over previous
//
#include <hip/hip_runtime.h>
#include <cstddef>
#include <math.h>

#define NN 50000
#define DEG 16
#define NEG_SLOPE 0.2f

__device__ inline unsigned pack_bf2(float lo, float hi) {
    unsigned ul = __float_as_uint(lo); ul = (ul + 0x7FFF + ((ul >> 16) & 1)) >> 16;
    unsigned uh = __float_as_uint(hi); uh = (uh + 0x7FFF + ((uh >> 16) & 1)) >> 16;
    return ul | (uh << 16);
}
__device__ inline float bf2f(unsigned short u) {
    return __uint_as_float(((unsigned)u) << 16);
}

// ---------------- GEMM [N,K] x [K,128] -> feat_bf16[N,128] + el/er (H heads) -----
// block 256 threads; 64 rows/block; each thread: 4 rows x 8 cols register tile.
// A tile stored k-major in LDS so the 4-row A fragment is one ds_read_b128
// (addr = kk*68 + ty*4 -> banks 4ty..4ty+3, broadcast across tx lanes: conflict-free).
template<int K, int H>
__launch_bounds__(256)
__global__ void gemm128_k(const float* __restrict__ A, const float* __restrict__ W,
                          const float* __restrict__ al, const float* __restrict__ ar,
                          unsigned short* __restrict__ feat, float* __restrict__ el,
                          float* __restrict__ er)
{
    __shared__ float As[32][68];      // k-major: As[kk][row], pad 68
    __shared__ float Bs[32 * 128];
    const int tid = threadIdx.x;
    const int tx = tid & 15;          // col group: cols 8*tx .. 8*tx+7
    const int ty = tid >> 4;          // rows ty*4 .. ty*4+3
    const int row0 = blockIdx.x * 64;

    float acc[4][8];
#pragma unroll
    for (int i = 0; i < 4; i++)
#pragma unroll
        for (int j = 0; j < 8; j++) acc[i][j] = 0.f;

    for (int kc = 0; kc < K; kc += 32) {
        __syncthreads();
        { // As: 64 rows x 32 k; 4 threads/row, 2 float4 each, transposed store
            int r = tid >> 2;
            int part = tid & 3;
            int gr = row0 + r; if (gr > NN - 1) gr = NN - 1;
            const float4* s4 = (const float4*)(A + (size_t)gr * K + kc);
            float4 v0 = s4[part * 2];
            float4 v1 = s4[part * 2 + 1];
            As[part * 8 + 0][r] = v0.x; As[part * 8 + 1][r] = v0.y;
            As[part * 8 + 2][r] = v0.z; As[part * 8 + 3][r] = v0.w;
            As[part * 8 + 4][r] = v1.x; As[part * 8 + 5][r] = v1.y;
            As[part * 8 + 6][r] = v1.z; As[part * 8 + 7][r] = v1.w;
        }
        { // Bs: rows kc..kc+31 of W, contiguous 4096 floats
            const float4* s4 = (const float4*)(W + (size_t)kc * 128);
            float4* d4 = (float4*)Bs;
#pragma unroll
            for (int q = 0; q < 4; q++) d4[tid + 256 * q] = s4[tid + 256 * q];
        }
        __syncthreads();
        const float4* Bs4 = (const float4*)Bs;
#pragma unroll
        for (int kk = 0; kk < 32; kk++) {
            float4 a4 = *(const float4*)&As[kk][ty * 4];
            float av[4] = {a4.x, a4.y, a4.z, a4.w};
            float4 b0 = Bs4[kk * 32 + tx * 2];
            float4 b1 = Bs4[kk * 32 + tx * 2 + 1];
#pragma unroll
            for (int i = 0; i < 4; i++) {
                float a = av[i];
                acc[i][0] += a * b0.x; acc[i][1] += a * b0.y;
                acc[i][2] += a * b0.z; acc[i][3] += a * b0.w;
                acc[i][4] += a * b1.x; acc[i][5] += a * b1.y;
                acc[i][6] += a * b1.z; acc[i][7] += a * b1.w;
            }
        }
    }

    // el/er: head h covers cols [h*128/H, (h+1)*128/H); G = lanes per head group
    constexpr int G = 16 / H;
    const int h = tx / G;
    float pel[4] = {0, 0, 0, 0}, per[4] = {0, 0, 0, 0};
#pragma unroll
    for (int j = 0; j < 8; j++) {
        float va = al[h * (128 / H) + (tx % G) * 8 + j];
        float vr = ar[h * (128 / H) + (tx % G) * 8 + j];
#pragma unroll
        for (int i = 0; i < 4; i++) { pel[i] += acc[i][j] * va; per[i] += acc[i][j] * vr; }
    }
#pragma unroll
    for (int m = 1; m < G; m <<= 1) {
#pragma unroll
        for (int i = 0; i < 4; i++) {
            pel[i] += __shfl_xor(pel[i], m);
            per[i] += __shfl_xor(per[i], m);
        }
    }
#pragma unroll
    for (int i = 0; i < 4; i++) {
        int r = row0 + ty * 4 + i;
        if (r < NN) {
            uint4 pk;
            pk.x = pack_bf2(acc[i][0], acc[i][1]);
            pk.y = pack_bf2(acc[i][2], acc[i][3]);
            pk.z = pack_bf2(acc[i][4], acc[i][5]);
            pk.w = pack_bf2(acc[i][6], acc[i][7]);
            *(uint4*)&feat[(size_t)r * 128 + tx * 8] = pk;
            if ((tx % G) == 0) { el[r * H + h] = pel[i]; er[r * H + h] = per[i]; }
        }
    }
}

// ---------------- edge softmax + aggregate, 128 cols bf16 gather, H heads --------
// one wave per dst node; lanes 0..15 hold the 16 in-edge logits per head group.
// gather: half-wave per row, 8B (ushort4) per lane, halves combined by shfl_xor(32).
template<int H>
__launch_bounds__(256)
__global__ void agg128_k(const unsigned short* __restrict__ feat, const float* __restrict__ el,
                         const float* __restrict__ er, const int* __restrict__ src,
                         const float* __restrict__ bias, float* __restrict__ out, int do_relu)
{
    __shared__ float s_alpha[4][16 * H];
    __shared__ int s_src[4][DEG];
    const int tid = threadIdx.x;
    const int w = tid >> 6, lane = tid & 63;
    const int node = blockIdx.x * 4 + w;
    const int j = lane & 15;
    const int h = lane >> 4;     // 0..3 (H=1: groups compute identical values)

    int s = src[node * DEG + j];
    float e;
    if (H == 4) e = el[s * 4 + h] + er[node * 4 + h];
    else        e = el[s] + er[node];
    e = (e > 0.f) ? e : NEG_SLOPE * e;
    float mx = e;
#pragma unroll
    for (int d = 1; d < 16; d <<= 1) mx = fmaxf(mx, __shfl_xor(mx, d));
    float ex = expf(e - mx);
    float den = ex;
#pragma unroll
    for (int d = 1; d < 16; d <<= 1) den += __shfl_xor(den, d);
    float alpha = ex / den;
    if (H == 4) s_alpha[w][h * 16 + j] = alpha;
    else if (lane < 16) s_alpha[w][j] = alpha;
    if (lane < 16) s_src[w][j] = s;
    __syncthreads();

    const int half = lane >> 5;   // row parity
    const int li = lane & 31;     // owns cols 4*li .. 4*li+3
    const int hd = li >> 3;       // head of this col group (H=4)
    float acc[4] = {0.f, 0.f, 0.f, 0.f};
#pragma unroll
    for (int jj2 = 0; jj2 < 8; jj2++) {
        int jj = jj2 * 2 + half;
        int sj = s_src[w][jj];
        float a = (H == 4) ? s_alpha[w][hd * 16 + jj] : s_alpha[w][jj];
        ushort4 v = *(const ushort4*)(feat + (size_t)sj * 128 + 4 * li);
        acc[0] += a * bf2f(v.x);
        acc[1] += a * bf2f(v.y);
        acc[2] += a * bf2f(v.z);
        acc[3] += a * bf2f(v.w);
    }
#pragma unroll
    for (int q = 0; q < 4; q++) acc[q] += __shfl_xor(acc[q], 32);
    if (half == 0) {
        float4 o;
        o.x = acc[0] + bias[4 * li + 0];
        o.y = acc[1] + bias[4 * li + 1];
        o.z = acc[2] + bias[4 * li + 2];
        o.w = acc[3] + bias[4 * li + 3];
        if (do_relu) {
            o.x = fmaxf(o.x, 0.f); o.y = fmaxf(o.y, 0.f);
            o.z = fmaxf(o.z, 0.f); o.w = fmaxf(o.w, 0.f);
        }
        *(float4*)&out[(size_t)node * 128 + 4 * li] = o;
    }
}

// ---------------- GEMM [N,128] x [128,40] -> feat2[N,40] + el2/er2 (1 head) ------
__launch_bounds__(256)
__global__ void gemm40_k(const float* __restrict__ A, const float* __restrict__ W,
                         const float* __restrict__ al, const float* __restrict__ ar,
                         float* __restrict__ feat, float* __restrict__ el, float* __restrict__ er)
{
    __shared__ float As[32][132];
    __shared__ float Ws[128 * 40];
    const int tid = threadIdx.x;
    const int tx = tid & 31;       // lanes tx<20 own cols {2tx, 2tx+1}
    const int ty = tid >> 5;       // rows ty*4 .. ty*4+3 (32 rows/block)
    const int row0 = blockIdx.x * 32;

    { // stage W2 (5120 floats) into LDS
        const float4* s4 = (const float4*)W;
        float4* d4 = (float4*)Ws;
#pragma unroll
        for (int q = 0; q < 5; q++) d4[tid + 256 * q] = s4[tid + 256 * q];
    }
    { // stage A rows: 32 x 128; 8 threads/row, 4 float4 each
        int r = tid >> 3;
        int gr = row0 + r; if (gr > NN - 1) gr = NN - 1;
        const float4* s4 = (const float4*)(A + (size_t)gr * 128);
#pragma unroll
        for (int q = 0; q < 4; q++) {
            float4 v = s4[(tid & 7) + 8 * q];
            *(float4*)&As[r][4 * ((tid & 7) + 8 * q)] = v;
        }
    }
    __syncthreads();

    const int ctx = (tx < 20) ? tx : 19;
    const float2* Wf2 = (const float2*)Ws;
    float acc[4][2] = {};
#pragma unroll 4
    for (int k = 0; k < 128; k++) {
        float2 wv = Wf2[k * 20 + ctx];
#pragma unroll
        for (int i = 0; i < 4; i++) {
            float a = As[ty * 4 + i][k];
            acc[i][0] += a * wv.x;
            acc[i][1] += a * wv.y;
        }
    }
    float pel[4], per[4];
#pragma unroll
    for (int i = 0; i < 4; i++) {
        float vl = 0.f, vr = 0.f;
        if (tx < 20) {
            vl = acc[i][0] * al[2 * ctx] + acc[i][1] * al[2 * ctx + 1];
            vr = acc[i][0] * ar[2 * ctx] + acc[i][1] * ar[2 * ctx + 1];
        }
        pel[i] = vl; per[i] = vr;
    }
#pragma unroll
    for (int m = 1; m < 32; m <<= 1) {   // reduce within 32-lane half-wave (= one ty)
#pragma unroll
        for (int i = 0; i < 4; i++) {
            pel[i] += __shfl_xor(pel[i], m);
            per[i] += __shfl_xor(per[i], m);
        }
    }
#pragma unroll
    for (int i = 0; i < 4; i++) {
        int r = row0 + ty * 4 + i;
        if (r < NN) {
            if (tx < 20) *(float2*)&feat[(size_t)r * 40 + 2 * tx] = make_float2(acc[i][0], acc[i][1]);
            if (tx == 0) { el[r] = pel[i]; er[r] = per[i]; }
        }
    }
}

// ---------------- edge softmax + aggregate 40 cols + log_softmax -----------------
__launch_bounds__(256)
__global__ void agg40_ls_k(const float* __restrict__ feat, const float* __restrict__ el,
                           const float* __restrict__ er, const int* __restrict__ src,
                           const float* __restrict__ bias, float* __restrict__ out)
{
    __shared__ float s_alpha[4][DEG];
    __shared__ int s_src[4][DEG];
    const int tid = threadIdx.x;
    const int w = tid >> 6, lane = tid & 63;
    const int node = blockIdx.x * 4 + w;
    const int j = lane & 15;

    int s = src[node * DEG + j];
    float e = el[s] + er[node];
    e = (e > 0.f) ? e : NEG_SLOPE * e;
    float mx = e;
#pragma unroll
    for (int d = 1; d < 16; d <<= 1) mx = fmaxf(mx, __shfl_xor(mx, d));
    float ex = expf(e - mx);
    float den = ex;
#pragma unroll
    for (int d = 1; d < 16; d <<= 1) den += __shfl_xor(den, d);
    if (lane < 16) { s_alpha[w][j] = ex / den; s_src[w][j] = s; }
    __syncthreads();

    float v;
    if (lane < 40) {
        float acc = 0.f;
#pragma unroll
        for (int jj = 0; jj < DEG; jj++)
            acc += s_alpha[w][jj] * feat[(size_t)s_src[w][jj] * 40 + lane];
        v = acc + bias[lane];
    } else v = -INFINITY;

    float m2 = v;
#pragma unroll
    for (int d = 1; d < 64; d <<= 1) m2 = fmaxf(m2, __shfl_xor(m2, d));
    float pe = (lane < 40) ? expf(v - m2) : 0.f;
    float se = pe;
#pragma unroll
    for (int d = 1; d < 64; d <<= 1) se += __shfl_xor(se, d);
    if (lane < 40) out[(size_t)node * 40 + lane] = v - m2 - logf(se);
}

extern "C" void kernel_launch(void* const* d_in, const int* in_sizes, int n_in,
                              void* d_out, int out_size, void* d_ws, size_t ws_size,
                              hipStream_t stream)
{
    const float* features = (const float*)d_in[0];
    const int*   src      = (const int*)d_in[1];
    // d_in[2] = dst: structurally repeat(arange(N),16) -> unused
    const float* W1  = (const float*)d_in[3];
    const float* al1 = (const float*)d_in[4];
    const float* ar1 = (const float*)d_in[5];
    const float* b1  = (const float*)d_in[6];
    const float* Wh  = (const float*)d_in[7];
    const float* alh = (const float*)d_in[8];
    const float* arh = (const float*)d_in[9];
    const float* bh  = (const float*)d_in[10];
    const float* W2  = (const float*)d_in[11];
    const float* al2 = (const float*)d_in[12];
    const float* ar2 = (const float*)d_in[13];
    const float* b2  = (const float*)d_in[14];
    float* out = (float*)d_out;

    float* ws = (float*)d_ws;
    unsigned short* featb = (unsigned short*)ws;   // N*128 bf16 (= N*64 floats)
    float* hb   = ws + (size_t)NN * 64;            // N*128 f32
    float* el1  = hb  + (size_t)NN * 128;          // N*4
    float* er1  = el1 + (size_t)NN * 4;            // N*4
    float* elA  = er1 + (size_t)NN * 4;            // N
    float* erA  = elA + NN;                        // N
    float* f40  = erA + NN;                        // N*40 f32

    dim3 blk(256);
    // layer 1: GATConv(256 -> 32x4 heads)
    gemm128_k<256, 4><<<782, blk, 0, stream>>>(features, W1, al1, ar1, featb, el1, er1);
    agg128_k<4><<<12500, blk, 0, stream>>>(featb, el1, er1, src, b1, hb, 1);
    // hidden: GATConv(128 -> 128, 1 head)
    gemm128_k<128, 1><<<782, blk, 0, stream>>>(hb, Wh, alh, arh, featb, elA, erA);
    agg128_k<1><<<12500, blk, 0, stream>>>(featb, elA, erA, src, bh, hb, 1);
    // layer 2: GATConv(128 -> 40, 1 head) + log_softmax
    gemm40_k<<<1563, blk, 0, stream>>>(hb, W2, al2, ar2, f40, elA, erA);
    agg40_ls_k<<<12500, blk, 0, stream>>>(f40, elA, erA, src, b2, out);
}

// Round 3
// 175.554 us; speedup vs baseline: 1.4046x; 1.1647x over previous
//
#include <hip/hip_runtime.h>
#include <cstddef>
#include <math.h>

#define NN 50000
#define DEG 16
#define NEG_SLOPE 0.2f

typedef __attribute__((ext_vector_type(8))) short bf16x8;
typedef __attribute__((ext_vector_type(4))) float f32x4;

__device__ inline unsigned short f2bf(float x) {
    unsigned u = __float_as_uint(x);
    return (unsigned short)((u + 0x7FFF + ((u >> 16) & 1)) >> 16);
}
__device__ inline float bf2f(unsigned short u) {
    return __uint_as_float(((unsigned)u) << 16);
}

// ---------------- W prep: Wt_hi/lo[c][k] (bf16) from W[k][c] (f32), 128 cols -----
__global__ void wprep_k(const float* __restrict__ W, unsigned short* __restrict__ Wh,
                        unsigned short* __restrict__ Wl, int K, int s)
{
    int idx = blockIdx.x * 256 + threadIdx.x;      // idx = c*K + k
    if (idx >= (128 << s)) return;
    int c = idx >> s, k = idx & (K - 1);
    float x = W[(size_t)k * 128 + c];
    unsigned short h = f2bf(x);
    Wh[idx] = h;
    Wl[idx] = f2bf(x - bf2f(h));
}

// ---------------- MFMA GEMM [N,K] x [K,128] -> feat_bf16 + el/er (H heads) -------
// block: 64 rows x 128 cols, 4 waves; wave w owns cols w*32 (2 col-frags of 16).
// Precision: A*W = Ah*Wh + Al*Wh + Ah*Wl (hi/lo bf16 split, ~2^-18 rel error).
// LDS A-tile in fragment-linear layout: frag f stride 544 elems, kgrp g stride 136,
// row r16*8 -> read addr = 16B*lane (conflict-free b128), writes spread (g+r16)%8.
template<int K, int H>
__launch_bounds__(256)
__global__ void gemm_mfma_k(const float* __restrict__ A,
                            const unsigned short* __restrict__ Wth,
                            const unsigned short* __restrict__ Wtl,
                            const float* __restrict__ al, const float* __restrict__ ar,
                            unsigned short* __restrict__ feat,
                            float* __restrict__ el, float* __restrict__ er)
{
    __shared__ __align__(16) unsigned short Ah[2176];
    __shared__ __align__(16) unsigned short Al[2176];
    __shared__ float redp[2][256];          // H==1 cross-wave el/er reduce
    const int tid = threadIdx.x;
    const int w = tid >> 6, l = tid & 63;
    const int lr = l & 15, lq = l >> 4;
    const int row0 = blockIdx.x * 64;
    const int cb = w * 32;

    f32x4 acc[4][2];
#pragma unroll
    for (int i = 0; i < 4; i++)
#pragma unroll
        for (int j = 0; j < 2; j++) acc[i][j] = (f32x4){0.f, 0.f, 0.f, 0.f};

    for (int kc = 0; kc < K; kc += 32) {
        __syncthreads();
        { // stage A chunk: thread -> row=tid>>2, kgrp=tid&3 (8 floats = 32B)
            const int row = tid >> 2, g = tid & 3;
            int gr = row0 + row; if (gr > NN - 1) gr = NN - 1;
            const float4* p = (const float4*)(A + (size_t)gr * K + kc + g * 8);
            float4 v0 = p[0], v1 = p[1];
            float xs[8] = {v0.x, v0.y, v0.z, v0.w, v1.x, v1.y, v1.z, v1.w};
            unsigned short hs[8], ls[8];
#pragma unroll
            for (int i = 0; i < 8; i++) {
                hs[i] = f2bf(xs[i]);
                ls[i] = f2bf(xs[i] - bf2f(hs[i]));
            }
            const int off = (row >> 4) * 544 + g * 136 + (row & 15) * 8;
            uint4 hw, lw;
            hw.x = (unsigned)hs[0] | ((unsigned)hs[1] << 16);
            hw.y = (unsigned)hs[2] | ((unsigned)hs[3] << 16);
            hw.z = (unsigned)hs[4] | ((unsigned)hs[5] << 16);
            hw.w = (unsigned)hs[6] | ((unsigned)hs[7] << 16);
            lw.x = (unsigned)ls[0] | ((unsigned)ls[1] << 16);
            lw.y = (unsigned)ls[2] | ((unsigned)ls[3] << 16);
            lw.z = (unsigned)ls[4] | ((unsigned)ls[5] << 16);
            lw.w = (unsigned)ls[6] | ((unsigned)ls[7] << 16);
            *(uint4*)&Ah[off] = hw;
            *(uint4*)&Al[off] = lw;
        }
        __syncthreads();

        bf16x8 bh[2], bl[2];
#pragma unroll
        for (int cf = 0; cf < 2; cf++) {   // B frag: lane -> col cb+cf*16+lr, k lq*8..+7
            const size_t bo = (size_t)(cb + cf * 16 + lr) * K + kc + lq * 8;
            bh[cf] = *(const bf16x8*)(Wth + bo);
            bl[cf] = *(const bf16x8*)(Wtl + bo);
        }
#pragma unroll
        for (int rf = 0; rf < 4; rf++) {
            const int aoff = rf * 544 + lq * 136 + lr * 8;
            bf16x8 af = *(bf16x8*)&Ah[aoff];
            bf16x8 lf = *(bf16x8*)&Al[aoff];
#pragma unroll
            for (int cf = 0; cf < 2; cf++) {
                acc[rf][cf] = __builtin_amdgcn_mfma_f32_16x16x32_bf16(af, bh[cf], acc[rf][cf], 0, 0, 0);
                acc[rf][cf] = __builtin_amdgcn_mfma_f32_16x16x32_bf16(lf, bh[cf], acc[rf][cf], 0, 0, 0);
                acc[rf][cf] = __builtin_amdgcn_mfma_f32_16x16x32_bf16(af, bl[cf], acc[rf][cf], 0, 0, 0);
            }
        }
    }

    // ---- epilogue: feat bf16 store + el/er ----
    // C/D map: row = rf*16 + lq*4 + reg, col = cb + cf*16 + lr
    const float a0 = al[cb + lr],      a1 = al[cb + 16 + lr];
    const float r0 = ar[cb + lr],      r1 = ar[cb + 16 + lr];
    float pel[4][4], per_[4][4];
#pragma unroll
    for (int rf = 0; rf < 4; rf++)
#pragma unroll
        for (int reg = 0; reg < 4; reg++) {
            pel[rf][reg]  = acc[rf][0][reg] * a0 + acc[rf][1][reg] * a1;
            per_[rf][reg] = acc[rf][0][reg] * r0 + acc[rf][1][reg] * r1;
        }
#pragma unroll
    for (int m = 1; m < 16; m <<= 1)
#pragma unroll
        for (int rf = 0; rf < 4; rf++)
#pragma unroll
            for (int reg = 0; reg < 4; reg++) {
                pel[rf][reg]  += __shfl_xor(pel[rf][reg], m);
                per_[rf][reg] += __shfl_xor(per_[rf][reg], m);
            }

#pragma unroll
    for (int rf = 0; rf < 4; rf++)
#pragma unroll
        for (int reg = 0; reg < 4; reg++) {
            const int r = row0 + rf * 16 + lq * 4 + reg;
            if (r < NN) {
#pragma unroll
                for (int cf = 0; cf < 2; cf++)
                    feat[(size_t)r * 128 + cb + cf * 16 + lr] = f2bf(acc[rf][cf][reg]);
            }
        }

    if (H == 4) {
        if (lr == 0) {
#pragma unroll
            for (int rf = 0; rf < 4; rf++)
#pragma unroll
                for (int reg = 0; reg < 4; reg++) {
                    const int r = row0 + rf * 16 + lq * 4 + reg;
                    if (r < NN) { el[r * 4 + w] = pel[rf][reg]; er[r * 4 + w] = per_[rf][reg]; }
                }
        }
    } else {
        if (lr == 0) {
#pragma unroll
            for (int rf = 0; rf < 4; rf++)
#pragma unroll
                for (int reg = 0; reg < 4; reg++) {
                    const int rl = rf * 16 + lq * 4 + reg;
                    redp[0][w * 64 + rl] = pel[rf][reg];
                    redp[1][w * 64 + rl] = per_[rf][reg];
                }
        }
        __syncthreads();
        if (tid < 64) {
            const int r = row0 + tid;
            if (r < NN) {
                el[r] = redp[0][tid] + redp[0][64 + tid] + redp[0][128 + tid] + redp[0][192 + tid];
                er[r] = redp[1][tid] + redp[1][64 + tid] + redp[1][128 + tid] + redp[1][192 + tid];
            }
        }
    }
}

// ---------------- edge softmax + aggregate, 128 cols bf16 gather, H heads --------
template<int H>
__launch_bounds__(256)
__global__ void agg128_k(const unsigned short* __restrict__ feat, const float* __restrict__ el,
                         const float* __restrict__ er, const int* __restrict__ src,
                         const float* __restrict__ bias, float* __restrict__ out, int do_relu)
{
    __shared__ float s_alpha[4][16 * H];
    __shared__ int s_src[4][DEG];
    const int tid = threadIdx.x;
    const int w = tid >> 6, lane = tid & 63;
    const int node = blockIdx.x * 4 + w;
    const int j = lane & 15;
    const int h = lane >> 4;

    int s = src[node * DEG + j];
    float e;
    if (H == 4) e = el[s * 4 + h] + er[node * 4 + h];
    else        e = el[s] + er[node];
    e = (e > 0.f) ? e : NEG_SLOPE * e;
    float mx = e;
#pragma unroll
    for (int d = 1; d < 16; d <<= 1) mx = fmaxf(mx, __shfl_xor(mx, d));
    float ex = expf(e - mx);
    float den = ex;
#pragma unroll
    for (int d = 1; d < 16; d <<= 1) den += __shfl_xor(den, d);
    float alpha = ex / den;
    if (H == 4) s_alpha[w][h * 16 + j] = alpha;
    else if (lane < 16) s_alpha[w][j] = alpha;
    if (lane < 16) s_src[w][j] = s;
    __syncthreads();

    const int half = lane >> 5;
    const int li = lane & 31;
    const int hd = li >> 3;
    float acc[4] = {0.f, 0.f, 0.f, 0.f};
#pragma unroll
    for (int jj2 = 0; jj2 < 8; jj2++) {
        int jj = jj2 * 2 + half;
        int sj = s_src[w][jj];
        float a = (H == 4) ? s_alpha[w][hd * 16 + jj] : s_alpha[w][jj];
        ushort4 v = *(const ushort4*)(feat + (size_t)sj * 128 + 4 * li);
        acc[0] += a * bf2f(v.x);
        acc[1] += a * bf2f(v.y);
        acc[2] += a * bf2f(v.z);
        acc[3] += a * bf2f(v.w);
    }
#pragma unroll
    for (int q = 0; q < 4; q++) acc[q] += __shfl_xor(acc[q], 32);
    if (half == 0) {
        float4 o;
        o.x = acc[0] + bias[4 * li + 0];
        o.y = acc[1] + bias[4 * li + 1];
        o.z = acc[2] + bias[4 * li + 2];
        o.w = acc[3] + bias[4 * li + 3];
        if (do_relu) {
            o.x = fmaxf(o.x, 0.f); o.y = fmaxf(o.y, 0.f);
            o.z = fmaxf(o.z, 0.f); o.w = fmaxf(o.w, 0.f);
        }
        *(float4*)&out[(size_t)node * 128 + 4 * li] = o;
    }
}

// ---------------- GEMM [N,128] x [128,40] -> feat2[N,40] + el2/er2 (1 head) ------
__launch_bounds__(256)
__global__ void gemm40_k(const float* __restrict__ A, const float* __restrict__ W,
                         const float* __restrict__ al, const float* __restrict__ ar,
                         float* __restrict__ feat, float* __restrict__ el, float* __restrict__ er)
{
    __shared__ float As[32][132];
    __shared__ float Ws[128 * 40];
    const int tid = threadIdx.x;
    const int tx = tid & 31;
    const int ty = tid >> 5;
    const int row0 = blockIdx.x * 32;

    {
        const float4* s4 = (const float4*)W;
        float4* d4 = (float4*)Ws;
#pragma unroll
        for (int q = 0; q < 5; q++) d4[tid + 256 * q] = s4[tid + 256 * q];
    }
    {
        int r = tid >> 3;
        int gr = row0 + r; if (gr > NN - 1) gr = NN - 1;
        const float4* s4 = (const float4*)(A + (size_t)gr * 128);
#pragma unroll
        for (int q = 0; q < 4; q++) {
            float4 v = s4[(tid & 7) + 8 * q];
            *(float4*)&As[r][4 * ((tid & 7) + 8 * q)] = v;
        }
    }
    __syncthreads();

    const int ctx = (tx < 20) ? tx : 19;
    const float2* Wf2 = (const float2*)Ws;
    float acc[4][2] = {};
#pragma unroll 4
    for (int k = 0; k < 128; k++) {
        float2 wv = Wf2[k * 20 + ctx];
#pragma unroll
        for (int i = 0; i < 4; i++) {
            float a = As[ty * 4 + i][k];
            acc[i][0] += a * wv.x;
            acc[i][1] += a * wv.y;
        }
    }
    float pel[4], per[4];
#pragma unroll
    for (int i = 0; i < 4; i++) {
        float vl = 0.f, vr = 0.f;
        if (tx < 20) {
            vl = acc[i][0] * al[2 * ctx] + acc[i][1] * al[2 * ctx + 1];
            vr = acc[i][0] * ar[2 * ctx] + acc[i][1] * ar[2 * ctx + 1];
        }
        pel[i] = vl; per[i] = vr;
    }
#pragma unroll
    for (int m = 1; m < 32; m <<= 1) {
#pragma unroll
        for (int i = 0; i < 4; i++) {
            pel[i] += __shfl_xor(pel[i], m);
            per[i] += __shfl_xor(per[i], m);
        }
    }
#pragma unroll
    for (int i = 0; i < 4; i++) {
        int r = row0 + ty * 4 + i;
        if (r < NN) {
            if (tx < 20) *(float2*)&feat[(size_t)r * 40 + 2 * tx] = make_float2(acc[i][0], acc[i][1]);
            if (tx == 0) { el[r] = pel[i]; er[r] = per[i]; }
        }
    }
}

// ---------------- edge softmax + aggregate 40 cols + log_softmax -----------------
__launch_bounds__(256)
__global__ void agg40_ls_k(const float* __restrict__ feat, const float* __restrict__ el,
                           const float* __restrict__ er, const int* __restrict__ src,
                           const float* __restrict__ bias, float* __restrict__ out)
{
    __shared__ float s_alpha[4][DEG];
    __shared__ int s_src[4][DEG];
    const int tid = threadIdx.x;
    const int w = tid >> 6, lane = tid & 63;
    const int node = blockIdx.x * 4 + w;
    const int j = lane & 15;

    int s = src[node * DEG + j];
    float e = el[s] + er[node];
    e = (e > 0.f) ? e : NEG_SLOPE * e;
    float mx = e;
#pragma unroll
    for (int d = 1; d < 16; d <<= 1) mx = fmaxf(mx, __shfl_xor(mx, d));
    float ex = expf(e - mx);
    float den = ex;
#pragma unroll
    for (int d = 1; d < 16; d <<= 1) den += __shfl_xor(den, d);
    if (lane < 16) { s_alpha[w][j] = ex / den; s_src[w][j] = s; }
    __syncthreads();

    float v;
    if (lane < 40) {
        float acc = 0.f;
#pragma unroll
        for (int jj = 0; jj < DEG; jj++)
            acc += s_alpha[w][jj] * feat[(size_t)s_src[w][jj] * 40 + lane];
        v = acc + bias[lane];
    } else v = -INFINITY;

    float m2 = v;
#pragma unroll
    for (int d = 1; d < 64; d <<= 1) m2 = fmaxf(m2, __shfl_xor(m2, d));
    float pe = (lane < 40) ? expf(v - m2) : 0.f;
    float se = pe;
#pragma unroll
    for (int d = 1; d < 64; d <<= 1) se += __shfl_xor(se, d);
    if (lane < 40) out[(size_t)node * 40 + lane] = v - m2 - logf(se);
}

extern "C" void kernel_launch(void* const* d_in, const int* in_sizes, int n_in,
                              void* d_out, int out_size, void* d_ws, size_t ws_size,
                              hipStream_t stream)
{
    const float* features = (const float*)d_in[0];
    const int*   src      = (const int*)d_in[1];
    // d_in[2] = dst: structurally repeat(arange(N),16) -> unused
    const float* W1  = (const float*)d_in[3];
    const float* al1 = (const float*)d_in[4];
    const float* ar1 = (const float*)d_in[5];
    const float* b1  = (const float*)d_in[6];
    const float* Wh  = (const float*)d_in[7];
    const float* alh = (const float*)d_in[8];
    const float* arh = (const float*)d_in[9];
    const float* bh  = (const float*)d_in[10];
    const float* W2  = (const float*)d_in[11];
    const float* al2 = (const float*)d_in[12];
    const float* ar2 = (const float*)d_in[13];
    const float* b2  = (const float*)d_in[14];
    float* out = (float*)d_out;

    float* ws = (float*)d_ws;
    unsigned short* featb = (unsigned short*)ws;   // N*128 bf16 (= N*64 floats)
    float* hb   = ws + (size_t)NN * 64;            // N*128 f32
    float* el1  = hb  + (size_t)NN * 128;          // N*4
    float* er1  = el1 + (size_t)NN * 4;            // N*4
    float* elA  = er1 + (size_t)NN * 4;            // N
    float* erA  = elA + NN;                        // N
    float* f40  = erA + NN;                        // N*40 f32
    unsigned short* Wt1h = (unsigned short*)(f40 + (size_t)NN * 40);  // 128*256
    unsigned short* Wt1l = Wt1h + 128 * 256;
    unsigned short* Wthh = Wt1l + 128 * 256;                          // 128*128
    unsigned short* Wthl = Wthh + 128 * 128;

    dim3 blk(256);
    // W prep (transpose + hi/lo bf16 split)
    wprep_k<<<128, blk, 0, stream>>>(W1, Wt1h, Wt1l, 256, 8);
    wprep_k<<<64,  blk, 0, stream>>>(Wh, Wthh, Wthl, 128, 7);
    // layer 1: GATConv(256 -> 32x4 heads)
    gemm_mfma_k<256, 4><<<782, blk, 0, stream>>>(features, Wt1h, Wt1l, al1, ar1, featb, el1, er1);
    agg128_k<4><<<12500, blk, 0, stream>>>(featb, el1, er1, src, b1, hb, 1);
    // hidden: GATConv(128 -> 128, 1 head)
    gemm_mfma_k<128, 1><<<782, blk, 0, stream>>>(hb, Wthh, Wthl, alh, arh, featb, elA, erA);
    agg128_k<1><<<12500, blk, 0, stream>>>(featb, elA, erA, src, bh, hb, 1);
    // layer 2: GATConv(128 -> 40, 1 head) + log_softmax
    gemm40_k<<<1563, blk, 0, stream>>>(hb, W2, al2, ar2, f40, elA, erA);
    agg40_ls_k<<<12500, blk, 0, stream>>>(f40, elA, erA, src, b2, out);
}